// Round 1
// baseline (291.060 us; speedup 1.0000x reference)
//
#include <hip/hip_runtime.h>
#include <hip/hip_bf16.h>
#include <cstdint>
#include <cstddef>

typedef short bf16x8 __attribute__((ext_vector_type(8)));
typedef float f32x4 __attribute__((ext_vector_type(4)));

#define EPS 1e-3f

__device__ __forceinline__ unsigned short f32_to_bf16(float f) {
    union { float f; uint32_t u; } v; v.f = f;
    uint32_t u = v.u;
    return (unsigned short)((u + 0x7FFFu + ((u >> 16) & 1u)) >> 16);
}

// K0: wt[k'][ci] = bf16(W[ci][k'])  (192x64), at[w][k] = bf16(A[p][v][w]) (32x96, k=p*25+v, zero-padded)
__global__ __launch_bounds__(256) void prep_kernel(const float* __restrict__ A,
                                                   const float* __restrict__ W,
                                                   unsigned short* __restrict__ wt,
                                                   unsigned short* __restrict__ at) {
    int idx = blockIdx.x * 256 + threadIdx.x;
    if (idx < 12288) {
        int kp = idx >> 6, ci = idx & 63;
        wt[idx] = f32_to_bf16(W[ci * 192 + kp]);
    } else {
        int j = idx - 12288;
        if (j < 3072) {
            int w = j / 96, k = j - w * 96;
            float val = 0.f;
            if (w < 25 && k < 75) {
                int p = k / 25, v = k - p * 25;
                val = A[(p * 25 + v) * 25 + w];
            }
            at[j] = f32_to_bf16(val);
        }
    }
}

// Kw: xw[n][ci][m][v] = sum_{l=max(0,m-8)}^{m} x[n][ci][l][v], stored bf16
__global__ __launch_bounds__(256) void window_kernel(const float* __restrict__ x,
                                                     unsigned short* __restrict__ xw) {
    int ci = blockIdx.x, n = blockIdx.y;
    __shared__ float sl[7500];
    const float* xp = x + (size_t)(n * 64 + ci) * 7500;
    for (int i = threadIdx.x; i < 7500; i += 256) sl[i] = xp[i];
    __syncthreads();
    ushort2* op = (ushort2*)(xw + (size_t)(n * 64 + ci) * 7500);
    for (int i = threadIdx.x; i < 3750; i += 256) {
        ushort2 r;
        {
            int e = 2 * i;
            int m = e / 25, w = e - m * 25;
            int lo = m - 8 > 0 ? m - 8 : 0;
            float t = 0.f;
            for (int l = lo; l <= m; ++l) t += sl[l * 25 + w];
            r.x = f32_to_bf16(t);
        }
        {
            int e = 2 * i + 1;
            int m = e / 25, w = e - m * 25;
            int lo = m - 8 > 0 ? m - 8 : 0;
            float t = 0.f;
            for (int l = lo; l <= m; ++l) t += sl[l * 25 + w];
            r.y = f32_to_bf16(t);
        }
        op[i] = r;
    }
}

// K1: y[n][k'][col] = sum_ci wt[k'][ci] * xw[n][ci][col]   (M=192, K=64, N=7500 per n)
__global__ __launch_bounds__(256) void conv_kernel(const unsigned short* __restrict__ xw,
                                                   const unsigned short* __restrict__ wt,
                                                   unsigned short* __restrict__ y) {
    int n = blockIdx.y;
    int col0 = blockIdx.x * 64;
    int tid = threadIdx.x;
    int wave = tid >> 6, lane = tid & 63, quad = lane >> 4, lcol = lane & 15;
    __shared__ unsigned short Xt[64][72];  // [local col][ci], 144B rows: 16B-aligned for b128
    const unsigned short* xb = xw + (size_t)n * 64 * 7500;
    #pragma unroll
    for (int e = 0; e < 16; ++e) {
        int gi = e * 256 + tid;
        int ci = gi >> 6, c = gi & 63;
        int col = col0 + c;
        Xt[c][ci] = (col < 7500) ? xb[(size_t)ci * 7500 + col] : (unsigned short)0;
    }
    __syncthreads();
    f32x4 acc[12];
    #pragma unroll
    for (int t = 0; t < 12; ++t) acc[t] = (f32x4){0.f, 0.f, 0.f, 0.f};
    int myc = wave * 16 + lcol;
    #pragma unroll
    for (int s = 0; s < 2; ++s) {
        bf16x8 bfrag = *(const bf16x8*)&Xt[myc][32 * s + quad * 8];
        const unsigned short* wp = wt + (size_t)(lcol * 64 + 32 * s + quad * 8);
        #pragma unroll
        for (int t = 0; t < 12; ++t) {
            bf16x8 afrag = *(const bf16x8*)(wp + t * 1024);  // (16t+lcol)*64 + ...
            acc[t] = __builtin_amdgcn_mfma_f32_16x16x32_bf16(afrag, bfrag, acc[t], 0, 0, 0);
        }
    }
    int col = col0 + myc;
    if (col < 7500) {
        unsigned short* yb = y + (size_t)n * 192 * 7500 + col;
        #pragma unroll
        for (int t = 0; t < 12; ++t) {
            #pragma unroll
            for (int r = 0; r < 4; ++r) {
                int kp = 16 * t + 4 * quad + r;
                yb[(size_t)kp * 7500] = f32_to_bf16(acc[t][r]);
            }
        }
    }
}

// K2: t[n][c][l][w] = sum_{p,v} y[n][c*3+p][l][v] * A[p][v][w]; then BN+ReLU+residual+ReLU
__global__ __launch_bounds__(256) void graph_bn_kernel(const unsigned short* __restrict__ y,
                                                       const unsigned short* __restrict__ at,
                                                       const float* __restrict__ x,
                                                       const float* __restrict__ gamma,
                                                       const float* __restrict__ beta,
                                                       const float* __restrict__ mean,
                                                       const float* __restrict__ var,
                                                       float* __restrict__ out) {
    int chunk = blockIdx.x, c = blockIdx.y, n = blockIdx.z;
    int l0b = chunk * 64;
    int tid = threadIdx.x;
    int wave = tid >> 6, lane = tid & 63, quad = lane >> 4, lcol = lane & 15;
    __shared__ unsigned short Ys[64][104];  // [local l][k=p*25+v], 208B rows: aligned + conflict-free
    for (int i = tid; i < 4800; i += 256) {
        int p = i / 1600, rem = i - p * 1600;
        int l = rem / 25, v = rem - l * 25;
        unsigned short val = 0;
        if (l0b + l < 300)
            val = y[((size_t)(n * 192 + c * 3 + p) * 300 + (l0b + l)) * 25 + v];
        Ys[l][p * 25 + v] = val;
    }
    // zero the k in [75,96) pad region so garbage (possible NaN bits) never enters MFMA
    for (int i = tid; i < 64 * 21; i += 256) {
        int l = i / 21, k = 75 + (i - l * 21);
        Ys[l][k] = 0;
    }
    __syncthreads();
    f32x4 acc0 = {0.f, 0.f, 0.f, 0.f}, acc1 = {0.f, 0.f, 0.f, 0.f};
    #pragma unroll
    for (int s = 0; s < 3; ++s) {
        bf16x8 af = *(const bf16x8*)&Ys[wave * 16 + lcol][32 * s + quad * 8];
        bf16x8 b0 = *(const bf16x8*)(at + (size_t)(lcol * 96 + 32 * s + quad * 8));
        bf16x8 b1 = *(const bf16x8*)(at + (size_t)((16 + lcol) * 96 + 32 * s + quad * 8));
        acc0 = __builtin_amdgcn_mfma_f32_16x16x32_bf16(af, b0, acc0, 0, 0, 0);
        acc1 = __builtin_amdgcn_mfma_f32_16x16x32_bf16(af, b1, acc1, 0, 0, 0);
    }
    float sc = gamma[c] * rsqrtf(var[c] + EPS);
    float sh = beta[c] - mean[c] * sc;
    #pragma unroll
    for (int nt = 0; nt < 2; ++nt) {
        f32x4 a = nt ? acc1 : acc0;
        int w = lcol + 16 * nt;
        #pragma unroll
        for (int r = 0; r < 4; ++r) {
            int l = l0b + wave * 16 + quad * 4 + r;
            if (l < 300 && w < 25) {
                size_t gi = ((size_t)(n * 64 + c) * 300 + l) * 25 + w;
                float xn = fmaxf(a[r] * sc + sh, 0.f);
                out[gi] = fmaxf(xn + x[gi], 0.f);
            }
        }
    }
}

extern "C" void kernel_launch(void* const* d_in, const int* in_sizes, int n_in,
                              void* d_out, int out_size, void* d_ws, size_t ws_size,
                              hipStream_t stream) {
    const float* x     = (const float*)d_in[0];
    const float* A     = (const float*)d_in[1];
    const float* W     = (const float*)d_in[2];
    const float* gamma = (const float*)d_in[3];
    const float* beta  = (const float*)d_in[4];
    const float* mean  = (const float*)d_in[5];
    const float* var   = (const float*)d_in[6];
    float* out = (float*)d_out;

    char* ws = (char*)d_ws;
    unsigned short* wt = (unsigned short*)ws;                          // 24,576 B
    unsigned short* at = (unsigned short*)(ws + 24576);                // 6,144 B
    unsigned short* xw = (unsigned short*)(ws + 30720);                // 30,720,000 B
    unsigned short* y  = (unsigned short*)(ws + 30720 + 30720000);     // 92,160,000 B
    // total ws use: ~122.9 MB

    prep_kernel<<<60, 256, 0, stream>>>(A, W, wt, at);
    window_kernel<<<dim3(64, 32), 256, 0, stream>>>(x, xw);
    conv_kernel<<<dim3(118, 32), 256, 0, stream>>>(xw, wt, y);
    graph_bn_kernel<<<dim3(5, 64, 32), 256, 0, stream>>>(y, at, x, gamma, beta, mean, var, out);
}

// Round 2
// 186.320 us; speedup vs baseline: 1.5622x; 1.5622x over previous
//
#include <hip/hip_runtime.h>
#include <cstdint>
#include <cstddef>

typedef short bf16x8 __attribute__((ext_vector_type(8)));
typedef float f32x4 __attribute__((ext_vector_type(4)));

#define EPS 1e-3f

__device__ __forceinline__ unsigned short f32_to_bf16(float f) {
    union { float f; uint32_t u; } v; v.f = f;
    uint32_t u = v.u;
    return (unsigned short)((u + 0x7FFFu + ((u >> 16) & 1u)) >> 16);
}

// K0: wt[kp][ci] = bf16(W[ci][kp])  (192x64), at[w][k] = bf16(A[p][v][w]) (32x96, k=p*25+v, zero-padded)
__global__ __launch_bounds__(256) void prep_kernel(const float* __restrict__ A,
                                                   const float* __restrict__ W,
                                                   unsigned short* __restrict__ wt,
                                                   unsigned short* __restrict__ at) {
    int idx = blockIdx.x * 256 + threadIdx.x;
    if (idx < 12288) {
        int kp = idx >> 6, ci = idx & 63;
        wt[idx] = f32_to_bf16(W[ci * 192 + kp]);
    } else {
        int j = idx - 12288;
        if (j < 3072) {
            int w = j / 96, k = j - w * 96;
            float val = 0.f;
            if (w < 25 && k < 75) {
                int p = k / 25, v = k - p * 25;
                val = A[(p * 25 + v) * 25 + w];
            }
            at[j] = f32_to_bf16(val);
        }
    }
}

// Kw: windowed x, chunk-major layout xw[n][ch=30][ci=64][256]
// element (ch, col) = window-sum at e = ch*250 + col (0 for e >= 7500)
__global__ __launch_bounds__(256) void window_kernel(const float* __restrict__ x,
                                                     unsigned short* __restrict__ xw) {
    int ci = blockIdx.x, n = blockIdx.y;
    __shared__ float sl[7500];
    const float4* xp4 = (const float4*)(x + (size_t)(n * 64 + ci) * 7500);
    float4* sl4 = (float4*)sl;
    for (int i = threadIdx.x; i < 1875; i += 256) sl4[i] = xp4[i];
    __syncthreads();
    unsigned short* base = xw + (size_t)n * 491520 + ci * 256;
    for (int i = threadIdx.x; i < 3840; i += 256) {
        int ch = i >> 7;
        int col = (i & 127) << 1;
        int e0 = ch * 250 + col;
        ushort2 r;
        #pragma unroll
        for (int h = 0; h < 2; ++h) {
            int e = e0 + h;
            float t = 0.f;
            if (e < 7500) {
                int m = e / 25, w = e - m * 25;
                int lo = m - 8 > 0 ? m - 8 : 0;
                for (int l = lo; l <= m; ++l) t += sl[l * 25 + w];
            }
            unsigned short b = f32_to_bf16(t);
            if (h == 0) r.x = b; else r.y = b;
        }
        *(ushort2*)(base + ch * 16384 + col) = r;
    }
}

// Fused conv(1x1) + graph matmul + BN + ReLU + residual + ReLU
// block = (chunk of 10 l, n). GEMM1: y[48][256] = wt_band * xw (B-frags in regs).
// Stage D->LDS [l=10][cl=16][104] as bf16, then GEMM2 vs at with fused epilogue.
__global__ __launch_bounds__(256, 2) void fused_kernel(
    const unsigned short* __restrict__ xw, const unsigned short* __restrict__ wt,
    const unsigned short* __restrict__ at, const float* __restrict__ x,
    const float* __restrict__ gamma, const float* __restrict__ beta,
    const float* __restrict__ mean, const float* __restrict__ var,
    float* __restrict__ out) {
    int chunk = blockIdx.x;   // 0..29
    int n = blockIdx.y;       // 0..31
    int l0 = chunk * 10;
    int tid = threadIdx.x;
    int wv = tid >> 6, lane = tid & 63, q = lane >> 4, lcol = lane & 15;

    __shared__ unsigned short Ys[160 * 104];
    __shared__ float scs[64], shs[64];

    if (tid < 64) {
        float sc = gamma[tid] * rsqrtf(var[tid] + EPS);
        scs[tid] = sc;
        shs[tid] = beta[tid] - mean[tid] * sc;
    }
    // zero the k in [72,104) pad region (k in [75,96) is read by MFMA and must be 0)
    for (int i = tid; i < 5120; i += 256) {
        int r = i >> 5, j = 72 + (i & 31);
        Ys[r * 104 + j] = 0;
    }

    // B1 fragments: xw[ci][col], k=ci. Gathered once, reused for all 4 c-groups.
    const unsigned short* xwb = xw + (size_t)n * 491520 + chunk * 16384;
    bf16x8 b1[4][2];
    #pragma unroll
    for (int nt = 0; nt < 4; ++nt) {
        #pragma unroll
        for (int s = 0; s < 2; ++s) {
            const unsigned short* p = xwb + (32 * s + 8 * q) * 256 + wv * 64 + nt * 16 + lcol;
            bf16x8 f;
            #pragma unroll
            for (int j = 0; j < 8; ++j) f[j] = (short)p[j * 256];
            b1[nt][s] = f;
        }
    }
    // B2 fragments: at[w][k], block-invariant
    bf16x8 b2[2][3];
    #pragma unroll
    for (int nt = 0; nt < 2; ++nt)
        #pragma unroll
        for (int s = 0; s < 3; ++s)
            b2[nt][s] = *(const bf16x8*)(at + (nt * 16 + lcol) * 96 + 32 * s + 8 * q);

    for (int g = 0; g < 4; ++g) {
        // GEMM1: M=48 (3 m-tiles), N=256 (4 n-tiles/wave), K=64
        f32x4 acc[3][4];
        #pragma unroll
        for (int mt = 0; mt < 3; ++mt)
            #pragma unroll
            for (int nt = 0; nt < 4; ++nt) acc[mt][nt] = (f32x4){0.f, 0.f, 0.f, 0.f};
        #pragma unroll
        for (int s = 0; s < 2; ++s) {
            #pragma unroll
            for (int mt = 0; mt < 3; ++mt) {
                bf16x8 a1 = *(const bf16x8*)(wt + (g * 48 + mt * 16 + lcol) * 64 + 32 * s + 8 * q);
                #pragma unroll
                for (int nt = 0; nt < 4; ++nt)
                    acc[mt][nt] = __builtin_amdgcn_mfma_f32_16x16x32_bf16(a1, b1[nt][s], acc[mt][nt], 0, 0, 0);
            }
        }
        __syncthreads();   // previous group's GEMM2 reads done; Ys free
        // stage D (rows kp_local = c_local*3+p) -> Ys[l][cl][p*25+v]
        #pragma unroll
        for (int mt = 0; mt < 3; ++mt) {
            #pragma unroll
            for (int nt = 0; nt < 4; ++nt) {
                int col = wv * 64 + nt * 16 + lcol;
                if (col < 250) {
                    int ll = col / 25, v = col - ll * 25;
                    int rowbase = ll * 16;
                    #pragma unroll
                    for (int r = 0; r < 4; ++r) {
                        int kp = mt * 16 + 4 * q + r;
                        int cl = kp / 3, p = kp - cl * 3;
                        Ys[(rowbase + cl) * 104 + p * 25 + v] = f32_to_bf16(acc[mt][nt][r]);
                    }
                }
            }
        }
        __syncthreads();
        // GEMM2 per l: M=16 (c_local), N=32 (w, 2 tiles), K=96; epilogue fused
        for (int l = wv; l < 10; l += 4) {
            f32x4 c0 = {0.f, 0.f, 0.f, 0.f}, c1 = {0.f, 0.f, 0.f, 0.f};
            #pragma unroll
            for (int s = 0; s < 3; ++s) {
                bf16x8 a2 = *(const bf16x8*)&Ys[(l * 16 + lcol) * 104 + 32 * s + 8 * q];
                c0 = __builtin_amdgcn_mfma_f32_16x16x32_bf16(a2, b2[0][s], c0, 0, 0, 0);
                c1 = __builtin_amdgcn_mfma_f32_16x16x32_bf16(a2, b2[1][s], c1, 0, 0, 0);
            }
            #pragma unroll
            for (int nt = 0; nt < 2; ++nt) {
                int w = nt * 16 + lcol;
                if (w < 25) {
                    f32x4 cc = nt ? c1 : c0;
                    #pragma unroll
                    for (int r = 0; r < 4; ++r) {
                        int c = g * 16 + 4 * q + r;
                        size_t gi = ((size_t)(n * 64 + c) * 300 + (l0 + l)) * 25 + w;
                        float o = fmaxf(cc[r] * scs[c] + shs[c], 0.f);
                        out[gi] = fmaxf(o + x[gi], 0.f);
                    }
                }
            }
        }
    }
}

extern "C" void kernel_launch(void* const* d_in, const int* in_sizes, int n_in,
                              void* d_out, int out_size, void* d_ws, size_t ws_size,
                              hipStream_t stream) {
    const float* x     = (const float*)d_in[0];
    const float* A     = (const float*)d_in[1];
    const float* W     = (const float*)d_in[2];
    const float* gamma = (const float*)d_in[3];
    const float* beta  = (const float*)d_in[4];
    const float* mean  = (const float*)d_in[5];
    const float* var   = (const float*)d_in[6];
    float* out = (float*)d_out;

    char* ws = (char*)d_ws;
    unsigned short* wt = (unsigned short*)ws;               // 24,576 B
    unsigned short* at = (unsigned short*)(ws + 24576);     // 6,144 B
    unsigned short* xw = (unsigned short*)(ws + 30720);     // 31,457,280 B

    prep_kernel<<<60, 256, 0, stream>>>(A, W, wt, at);
    window_kernel<<<dim3(64, 32), 256, 0, stream>>>(x, xw);
    fused_kernel<<<dim3(30, 32), 256, 0, stream>>>(xw, wt, at, x, gamma, beta, mean, var, out);
}

// Round 3
// 167.355 us; speedup vs baseline: 1.7392x; 1.1133x over previous
//
#include <hip/hip_runtime.h>
#include <cstdint>
#include <cstddef>

typedef short bf16x8 __attribute__((ext_vector_type(8)));
typedef float f32x4 __attribute__((ext_vector_type(4)));

#define EPS 1e-3f

__device__ __forceinline__ short f32_to_bf16s(float f) {
    union { float f; uint32_t u; } v; v.f = f;
    uint32_t u = v.u;
    return (short)((u + 0x7FFFu + ((u >> 16) & 1u)) >> 16);
}

// K0: wt[kp][ci] = bf16(W[ci][kp]) (192x64); at[w][k] = bf16(A[p][v][w]) (32x96, k=p*25+v, zero-padded)
__global__ __launch_bounds__(256) void prep_kernel(const float* __restrict__ A,
                                                   const float* __restrict__ W,
                                                   unsigned short* __restrict__ wt,
                                                   unsigned short* __restrict__ at) {
    int idx = blockIdx.x * 256 + threadIdx.x;
    if (idx < 12288) {
        int kp = idx >> 6, ci = idx & 63;
        wt[idx] = (unsigned short)f32_to_bf16s(W[ci * 192 + kp]);
    } else {
        int j = idx - 12288;
        if (j < 3072) {
            int w = j / 96, k = j - w * 96;
            float val = 0.f;
            if (w < 25 && k < 75) {
                int p = k / 25, v = k - p * 25;
                val = A[(p * 25 + v) * 25 + w];
            }
            at[j] = (unsigned short)f32_to_bf16s(val);
        }
    }
}

// Mega: in-LDS temporal window + conv(1x1) GEMM + graph GEMM + BN/ReLU/residual/ReLU.
// Block = (l-chunk of 10, n), 512 threads (8 waves).
// LDS union: phase 1/2 -> xwL[qs=ci>>3][col=l*25+v][j=ci&7], row stride 2056 shorts;
//            phase 3+  -> Ys[l*16+cl][104] (k=p*25+v, pad zeroed).
__global__ __launch_bounds__(512, 4) void mega_kernel(
    const float* __restrict__ x,
    const unsigned short* __restrict__ wt,
    const unsigned short* __restrict__ at,
    const float* __restrict__ gamma, const float* __restrict__ beta,
    const float* __restrict__ mean, const float* __restrict__ var,
    float* __restrict__ out) {
    int ch = blockIdx.x, n = blockIdx.y;
    int l0 = ch * 10;
    int tid = threadIdx.x;
    int wv = tid >> 6, lane = tid & 63, q = lane >> 4, lcol = lane & 15;

    __shared__ short smem[16640];          // 33,280 B (max of xwL 16448 / Ys 16640 shorts)
    __shared__ float scs[64], shs[64];

    if (tid < 64) {
        float sc = gamma[tid] * rsqrtf(var[tid] + EPS);
        scs[tid] = sc;
        shs[tid] = beta[tid] - mean[tid] * sc;
    }

    // Phase 1: per-column (ci,v) running 9-window over l = l0..l0+9, write bf16 to xwL
    #pragma unroll 1
    for (int rep = 0; rep < 4; ++rep) {
        int cidx = tid + rep * 512;
        if (cidx < 1600) {
            int ci = cidx / 25, v = cidx - ci * 25;
            const float* xp = x + (size_t)(n * 64 + ci) * 7500 + v;
            float vals[18];
            #pragma unroll
            for (int i = 0; i < 18; ++i) {
                int l = l0 - 8 + i;
                vals[i] = (l >= 0) ? xp[l * 25] : 0.f;   // l0+9 <= 299 always
            }
            float run = 0.f;
            #pragma unroll
            for (int i = 0; i < 8; ++i) run += vals[i];
            int base = (ci >> 3) * 2056 + (ci & 7);
            #pragma unroll
            for (int j = 0; j < 10; ++j) {
                run += vals[j + 8];
                smem[base + (j * 25 + v) * 8] = f32_to_bf16s(run);
                run -= vals[j];
            }
        }
    }
    __syncthreads();

    // B1 fragments (GEMM1): k = 32s+8q+j, col = wv*32 + nt*16 + lcol  -> aligned ds_read_b128
    bf16x8 b1[2][2];
    #pragma unroll
    for (int nt = 0; nt < 2; ++nt)
        #pragma unroll
        for (int s = 0; s < 2; ++s) {
            int col = wv * 32 + nt * 16 + lcol;
            b1[nt][s] = *(const bf16x8*)&smem[(4 * s + q) * 2056 + col * 8];
        }
    // B2 fragments (GEMM2): at[w][k], block-invariant, from L2
    bf16x8 b2[2][3];
    #pragma unroll
    for (int nt = 0; nt < 2; ++nt)
        #pragma unroll
        for (int s = 0; s < 3; ++s)
            b2[nt][s] = *(const bf16x8*)(at + (size_t)(nt * 16 + lcol) * 96 + 32 * s + 8 * q);
    __syncthreads();   // xwL fully consumed; smem becomes Ys

    // zero Ys pad region k in [72,104) (MFMA reads k<96; [72,75) re-written by staging)
    for (int i = tid; i < 5120; i += 512) {
        int r = i >> 5, jj = 72 + (i & 31);
        smem[r * 104 + jj] = 0;
    }

    for (int g = 0; g < 4; ++g) {
        // GEMM1: M=48 (kp rows of c-group g), N=256, K=64
        f32x4 acc[3][2];
        #pragma unroll
        for (int mt = 0; mt < 3; ++mt)
            #pragma unroll
            for (int nt = 0; nt < 2; ++nt) acc[mt][nt] = (f32x4){0.f, 0.f, 0.f, 0.f};
        #pragma unroll
        for (int s = 0; s < 2; ++s)
            #pragma unroll
            for (int mt = 0; mt < 3; ++mt) {
                bf16x8 a1 = *(const bf16x8*)(wt + (size_t)(g * 48 + mt * 16 + lcol) * 64 + 32 * s + 8 * q);
                #pragma unroll
                for (int nt = 0; nt < 2; ++nt)
                    acc[mt][nt] = __builtin_amdgcn_mfma_f32_16x16x32_bf16(a1, b1[nt][s], acc[mt][nt], 0, 0, 0);
            }
        __syncthreads();   // previous group's GEMM2 reads (and pad zeroing / b1 loads) complete
        // Stage D -> Ys[l][cl][p*25+v]
        #pragma unroll
        for (int mt = 0; mt < 3; ++mt)
            #pragma unroll
            for (int nt = 0; nt < 2; ++nt) {
                int col = wv * 32 + nt * 16 + lcol;
                if (col < 250) {
                    int ll = col / 25, v = col - ll * 25;
                    #pragma unroll
                    for (int r = 0; r < 4; ++r) {
                        int kp = mt * 16 + 4 * q + r;
                        int cl = kp / 3, p = kp - cl * 3;
                        smem[(ll * 16 + cl) * 104 + p * 25 + v] = f32_to_bf16s(acc[mt][nt][r]);
                    }
                }
            }
        __syncthreads();
        // GEMM2 per l: M=16 (c_local), N=32 (w), K=96; fused epilogue
        for (int l = wv; l < 10; l += 8) {
            f32x4 c0 = {0.f, 0.f, 0.f, 0.f}, c1 = {0.f, 0.f, 0.f, 0.f};
            #pragma unroll
            for (int s = 0; s < 3; ++s) {
                bf16x8 a2 = *(const bf16x8*)&smem[(l * 16 + lcol) * 104 + 32 * s + 8 * q];
                c0 = __builtin_amdgcn_mfma_f32_16x16x32_bf16(a2, b2[0][s], c0, 0, 0, 0);
                c1 = __builtin_amdgcn_mfma_f32_16x16x32_bf16(a2, b2[1][s], c1, 0, 0, 0);
            }
            #pragma unroll
            for (int nt = 0; nt < 2; ++nt) {
                int w = nt * 16 + lcol;
                if (w < 25) {
                    f32x4 cc = nt ? c1 : c0;
                    #pragma unroll
                    for (int r = 0; r < 4; ++r) {
                        int c = g * 16 + 4 * q + r;
                        size_t gi = ((size_t)(n * 64 + c) * 300 + (l0 + l)) * 25 + w;
                        float o = fmaxf(cc[r] * scs[c] + shs[c], 0.f);
                        out[gi] = fmaxf(o + x[gi], 0.f);   // x row is L2-hot from phase 1
                    }
                }
            }
        }
    }
}

extern "C" void kernel_launch(void* const* d_in, const int* in_sizes, int n_in,
                              void* d_out, int out_size, void* d_ws, size_t ws_size,
                              hipStream_t stream) {
    const float* x     = (const float*)d_in[0];
    const float* A     = (const float*)d_in[1];
    const float* W     = (const float*)d_in[2];
    const float* gamma = (const float*)d_in[3];
    const float* beta  = (const float*)d_in[4];
    const float* mean  = (const float*)d_in[5];
    const float* var   = (const float*)d_in[6];
    float* out = (float*)d_out;

    char* ws = (char*)d_ws;
    unsigned short* wt = (unsigned short*)ws;               // 24,576 B
    unsigned short* at = (unsigned short*)(ws + 24576);     // 6,144 B

    prep_kernel<<<60, 256, 0, stream>>>(A, W, wt, at);
    mega_kernel<<<dim3(30, 32), 512, 0, stream>>>(x, wt, at, gamma, beta, mean, var, out);
}